// Round 7
// baseline (333.655 us; speedup 1.0000x reference)
//
#include <hip/hip_runtime.h>

#define NDIM 128
#define BKT_SHIFT 9            // 512 nodes per bucket
#define BKT_NODES 512
#define BKT_CAP   12288        // edges capacity per bucket (mean ~8163)
#define PART_CHUNK 4096        // edges per block in partition kernel

typedef unsigned short u16;
typedef unsigned int u32;
typedef __attribute__((ext_vector_type(8))) short bf16x8;
typedef __attribute__((ext_vector_type(4))) float f32x4;

__device__ inline u16 f2bf(float f) {
    u32 u = __float_as_uint(f);
    u += 0x7fffu + ((u >> 16) & 1u);   // RNE
    return (u16)(u >> 16);
}
__device__ inline float bf2f(u16 h) { return __uint_as_float((u32)h << 16); }

// ---------------- bucketed CSR build (unchanged — working) ----------------

__global__ __launch_bounds__(256) void partition_kernel(
    const int* __restrict__ ei, int E,
    int* __restrict__ gcur, u32* __restrict__ ebuf) {
    __shared__ int hcnt[256];
    __shared__ int hbase[256];
    const int tid = threadIdx.x;
    const int base = blockIdx.x * PART_CHUNK;
    hcnt[tid] = 0;
    __syncthreads();

    u32 val[16];
    int bkt[16];
    #pragma unroll
    for (int k = 0; k < 16; ++k) {
        int e = base + k * 256 + tid;
        bkt[k] = -1;
        if (e < E) {
            int src = ei[e];
            int dst = ei[(size_t)E + e];
            int b = dst >> BKT_SHIFT;
            bkt[k] = b;
            val[k] = ((u32)src << BKT_SHIFT) | (u32)(dst & (BKT_NODES - 1));
            atomicAdd(&hcnt[b], 1);
        }
    }
    __syncthreads();
    {
        int c = hcnt[tid];
        if (c > 0) hbase[tid] = atomicAdd(&gcur[tid], c);
        hcnt[tid] = 0;   // reuse as rank counter
    }
    __syncthreads();
    #pragma unroll
    for (int k = 0; k < 16; ++k) {
        if (bkt[k] >= 0) {
            int b = bkt[k];
            int r = atomicAdd(&hcnt[b], 1);
            int off = hbase[b] + r;
            if (off < BKT_CAP)
                ebuf[(size_t)b * BKT_CAP + off] = val[k];
        }
    }
}

__global__ __launch_bounds__(256) void bucket_csr_kernel(
    const int* __restrict__ gcur, const u32* __restrict__ ebuf,
    int* __restrict__ row_beg, int* __restrict__ degN,
    int* __restrict__ col, int n) {
    __shared__ int deg_l[BKT_NODES];
    __shared__ int pre_l[BKT_NODES];
    __shared__ int cur_l[BKT_NODES];
    __shared__ int wsum[4];
    const int tid = threadIdx.x;
    const int lane = tid & 63, wid = tid >> 6;
    const int b = blockIdx.x;
    const int node0 = b << BKT_SHIFT;
    int cnt = gcur[b];
    if (cnt > BKT_CAP) cnt = BKT_CAP;
    const size_t ebase = (size_t)b * BKT_CAP;

    deg_l[tid] = 0; deg_l[tid + 256] = 0;
    cur_l[tid] = 0; cur_l[tid + 256] = 0;
    __syncthreads();

    for (int i = tid; i < cnt; i += 256)
        atomicAdd(&deg_l[ebuf[ebase + i] & (BKT_NODES - 1)], 1);
    __syncthreads();

    int v0 = deg_l[2 * tid], v1 = deg_l[2 * tid + 1];
    int s = v0 + v1, inc = s;
    #pragma unroll
    for (int d = 1; d < 64; d <<= 1) {
        int t = __shfl_up(inc, d, 64);
        if (lane >= d) inc += t;
    }
    if (lane == 63) wsum[wid] = inc;
    __syncthreads();
    int woff = 0;
    for (int w = 0; w < wid; ++w) woff += wsum[w];
    int ex = woff + (inc - s);
    pre_l[2 * tid] = ex;
    pre_l[2 * tid + 1] = ex + v0;
    __syncthreads();

    #pragma unroll
    for (int p = 0; p < 2; ++p) {
        int idx = tid + p * 256;
        int node = node0 + idx;
        if (node < n) {
            row_beg[node] = (int)ebase + pre_l[idx];
            degN[node]    = deg_l[idx];
        }
    }

    for (int i = tid; i < cnt; i += 256) {
        u32 v = ebuf[ebase + i];
        int d = v & (BKT_NODES - 1);
        int r = atomicAdd(&cur_l[d], 1);
        col[ebase + pre_l[d] + r] = (int)(v >> BKT_SHIFT);
    }
}

// ---------------- weight prep: Wt[o][k] split bf16 hi/lo, k = [w_l | w_r] ----------------

__global__ void build_wt_kernel(const float* __restrict__ wl,
                                const float* __restrict__ wr,
                                u16* __restrict__ wth, u16* __restrict__ wtl) {
    int idx = blockIdx.x * blockDim.x + threadIdx.x;
    if (idx >= 128 * 256) return;
    int o = idx >> 8, k = idx & 255;
    float v = (k < 128) ? wl[o * 128 + k] : wr[o * 128 + (k - 128)];
    u16 hi = f2bf(v);
    wth[idx] = hi;
    wtl[idx] = f2bf(v - bf2f(hi));
}

// ---------------- fp32 -> bf16(hi) table ----------------

__global__ __launch_bounds__(256) void to_bf16_kernel(
    const float* __restrict__ in, u16* __restrict__ out, int n4) {
    int stride = gridDim.x * blockDim.x;
    for (int i = blockIdx.x * blockDim.x + threadIdx.x; i < n4; i += stride) {
        float4 v = *(const float4*)&in[(size_t)i * 4];
        ushort4 o;
        o.x = f2bf(v.x); o.y = f2bf(v.y); o.z = f2bf(v.z); o.w = f2bf(v.w);
        *(ushort4*)&out[(size_t)i * 4] = o;
    }
}

// ---------------- mean aggregation: bf16 gather, fp32 accum, split hi/lo out ----------------

__device__ inline void accum8(float acc[8], uint4 u) {
    const u32* p = (const u32*)&u;
    #pragma unroll
    for (int q = 0; q < 4; ++q) {
        u32 w = p[q];
        acc[2 * q]     += __uint_as_float(w << 16);
        acc[2 * q + 1] += __uint_as_float(w & 0xffff0000u);
    }
}

__global__ __launch_bounds__(256) void aggregate_bf16_kernel(
    const u16* __restrict__ feat, const int* __restrict__ row_beg,
    const int* __restrict__ degN, const int* __restrict__ col,
    u16* __restrict__ aggh, u16* __restrict__ aggl, int n) {
    int node = blockIdx.x * 16 + (threadIdx.x >> 4);
    if (node >= n) return;
    int l = threadIdx.x & 15;   // dims [8l, 8l+8)
    int beg = row_beg[node];
    int dg  = degN[node];
    int end = beg + dg;
    float acc[8] = {0.f, 0.f, 0.f, 0.f, 0.f, 0.f, 0.f, 0.f};
    int j = beg;
    for (; j + 4 <= end; j += 4) {
        int s0 = col[j], s1 = col[j + 1], s2 = col[j + 2], s3 = col[j + 3];
        uint4 u0 = *(const uint4*)&feat[(size_t)s0 * NDIM + l * 8];
        uint4 u1 = *(const uint4*)&feat[(size_t)s1 * NDIM + l * 8];
        uint4 u2 = *(const uint4*)&feat[(size_t)s2 * NDIM + l * 8];
        uint4 u3 = *(const uint4*)&feat[(size_t)s3 * NDIM + l * 8];
        accum8(acc, u0); accum8(acc, u1); accum8(acc, u2); accum8(acc, u3);
    }
    for (; j < end; ++j) {
        uint4 u = *(const uint4*)&feat[(size_t)col[j] * NDIM + l * 8];
        accum8(acc, u);
    }
    float inv = (dg > 0) ? 1.0f / (float)dg : 0.f;
    u16 hs[8], ls[8];
    #pragma unroll
    for (int q = 0; q < 8; ++q) {
        float v = acc[q] * inv;
        u16 hi = f2bf(v);
        hs[q] = hi;
        ls[q] = f2bf(v - bf2f(hi));
    }
    *(ushort4*)&aggh[(size_t)node * NDIM + l * 8]     = make_ushort4(hs[0], hs[1], hs[2], hs[3]);
    *(ushort4*)&aggh[(size_t)node * NDIM + l * 8 + 4] = make_ushort4(hs[4], hs[5], hs[6], hs[7]);
    *(ushort4*)&aggl[(size_t)node * NDIM + l * 8]     = make_ushort4(ls[0], ls[1], ls[2], ls[3]);
    *(ushort4*)&aggl[(size_t)node * NDIM + l * 8 + 4] = make_ushort4(ls[4], ls[5], ls[6], ls[7]);
}

// ---------------- MFMA GEMM: out = [agg | xh] @ Wt^T + bias ----------------
// Block = 64 rows x 128 cols, 4 waves side-by-side; wave = 64 rows x 32 cols
// (mt=4, nt=2). Smaller tile -> 1563 blocks (~24 waves/CU) to fix the
// occupancy/latency limit seen in R6 (15.7% occ, MfmaUtil 8%).

__global__ __launch_bounds__(256, 4) void gemm_mfma_kernel(
    const u16* __restrict__ aggh, const u16* __restrict__ aggl,
    const u16* __restrict__ xh,
    const u16* __restrict__ wth, const u16* __restrict__ wtl,
    const float* __restrict__ bias,
    float* __restrict__ outF, u16* __restrict__ outH,
    int M, int do_relu) {
    const int tid  = threadIdx.x;
    const int lane = tid & 63;
    const int wid  = tid >> 6;                 // wave 0..3 -> col strip of 32
    const int rr = lane & 15, kb = lane >> 4;  // rr: row/col-in-tile, kb: k-block
    const int m0 = blockIdx.x * 64;

    int arow[4];
    #pragma unroll
    for (int mt = 0; mt < 4; ++mt) {
        int r = m0 + mt * 16 + rr;
        arow[mt] = (r < M) ? r : (M - 1);
    }
    const u16* wthp[2]; const u16* wtlp[2];
    #pragma unroll
    for (int nt = 0; nt < 2; ++nt) {
        int c = wid * 32 + nt * 16 + rr;
        wthp[nt] = &wth[(size_t)c * 256];
        wtlp[nt] = &wtl[(size_t)c * 256];
    }

    f32x4 acc[4][2];
    #pragma unroll
    for (int mt = 0; mt < 4; ++mt)
        #pragma unroll
        for (int nt = 0; nt < 2; ++nt)
            acc[mt][nt] = (f32x4){0.f, 0.f, 0.f, 0.f};

    #pragma unroll
    for (int ks = 0; ks < 8; ++ks) {
        const int kfrag = ks * 32 + kb * 8;      // k offset of this lane's 8 elems
        bf16x8 bh[2], bl[2];
        #pragma unroll
        for (int nt = 0; nt < 2; ++nt) {
            bh[nt] = *(const bf16x8*)&wthp[nt][kfrag];
            bl[nt] = *(const bf16x8*)&wtlp[nt][kfrag];
        }
        if (ks < 4) {
            const int ka = ks * 32 + kb * 8;
            bf16x8 ah[4], al[4];
            #pragma unroll
            for (int mt = 0; mt < 4; ++mt) {
                ah[mt] = *(const bf16x8*)&aggh[(size_t)arow[mt] * NDIM + ka];
                al[mt] = *(const bf16x8*)&aggl[(size_t)arow[mt] * NDIM + ka];
            }
            #pragma unroll
            for (int mt = 0; mt < 4; ++mt)
                #pragma unroll
                for (int nt = 0; nt < 2; ++nt) {
                    acc[mt][nt] = __builtin_amdgcn_mfma_f32_16x16x32_bf16(ah[mt], bh[nt], acc[mt][nt], 0, 0, 0);
                    acc[mt][nt] = __builtin_amdgcn_mfma_f32_16x16x32_bf16(al[mt], bh[nt], acc[mt][nt], 0, 0, 0);
                    acc[mt][nt] = __builtin_amdgcn_mfma_f32_16x16x32_bf16(ah[mt], bl[nt], acc[mt][nt], 0, 0, 0);
                }
        } else {
            const int ka = (ks - 4) * 32 + kb * 8;
            bf16x8 ah[4];
            #pragma unroll
            for (int mt = 0; mt < 4; ++mt)
                ah[mt] = *(const bf16x8*)&xh[(size_t)arow[mt] * NDIM + ka];
            #pragma unroll
            for (int mt = 0; mt < 4; ++mt)
                #pragma unroll
                for (int nt = 0; nt < 2; ++nt) {
                    acc[mt][nt] = __builtin_amdgcn_mfma_f32_16x16x32_bf16(ah[mt], bh[nt], acc[mt][nt], 0, 0, 0);
                    acc[mt][nt] = __builtin_amdgcn_mfma_f32_16x16x32_bf16(ah[mt], bl[nt], acc[mt][nt], 0, 0, 0);
                }
        }
    }

    // epilogue: D col = rr, row = kb*4 + reg
    #pragma unroll
    for (int nt = 0; nt < 2; ++nt) {
        int gcol = wid * 32 + nt * 16 + rr;
        float bb = bias[gcol];
        #pragma unroll
        for (int mt = 0; mt < 4; ++mt) {
            #pragma unroll
            for (int r = 0; r < 4; ++r) {
                int grow = m0 + mt * 16 + kb * 4 + r;
                if (grow < M) {
                    float v = acc[mt][nt][r] + bb;
                    if (do_relu) v = fmaxf(v, 0.f);
                    if (outF) outF[(size_t)grow * NDIM + gcol] = v;
                    if (outH) outH[(size_t)grow * NDIM + gcol] = f2bf(v);
                }
            }
        }
    }
}

// ---------------- launch ----------------

extern "C" void kernel_launch(void* const* d_in, const int* in_sizes, int n_in,
                              void* d_out, int out_size, void* d_ws, size_t ws_size,
                              hipStream_t stream) {
    const float* x    = (const float*)d_in[0];
    const int*   ei   = (const int*)d_in[1];
    const float* w1_l = (const float*)d_in[2];
    const float* b1   = (const float*)d_in[3];
    const float* w1_r = (const float*)d_in[4];
    const float* w2_l = (const float*)d_in[5];
    const float* b2   = (const float*)d_in[6];
    const float* w2_r = (const float*)d_in[7];
    const int N = in_sizes[0] / NDIM;
    const int E = in_sizes[1] / 2;
    float* out = (float*)d_out;

    const int NB = (N + BKT_NODES - 1) >> BKT_SHIFT;

    char* ws = (char*)d_ws;
    size_t off = 0;
    auto take = [&](size_t bytes) -> char* {
        char* p = ws + off;
        off += (bytes + 255) & ~(size_t)255;
        return p;
    };
    int* row_beg = (int*)take((size_t)N * 4);
    int* degN    = (int*)take((size_t)N * 4);
    int* gcur    = (int*)take((size_t)NB * 4);
    u32* ebuf    = (u32*)take((size_t)NB * BKT_CAP * 4);
    int* colA    = (int*)take((size_t)NB * BKT_CAP * 4);
    u16* wt1h    = (u16*)take(128 * 256 * 2);
    u16* wt1l    = (u16*)take(128 * 256 * 2);
    u16* wt2h    = (u16*)take(128 * 256 * 2);
    u16* wt2l    = (u16*)take(128 * 256 * 2);
    u16* aggh    = (u16*)take((size_t)N * NDIM * 2);
    u16* aggl    = (u16*)take((size_t)N * NDIM * 2);
    u16* hh      = (u16*)take((size_t)N * NDIM * 2);
    // xh lives in d_out: free scratch until the layer-2 epilogue overwrites it
    u16* xh      = (u16*)d_out;

    hipMemsetAsync(gcur, 0, (size_t)NB * 4, stream);
    partition_kernel<<<(E + PART_CHUNK - 1) / PART_CHUNK, 256, 0, stream>>>(ei, E, gcur, ebuf);
    bucket_csr_kernel<<<NB, 256, 0, stream>>>(gcur, ebuf, row_beg, degN, colA, N);
    build_wt_kernel<<<128, 256, 0, stream>>>(w1_l, w1_r, wt1h, wt1l);
    build_wt_kernel<<<128, 256, 0, stream>>>(w2_l, w2_r, wt2h, wt2l);
    to_bf16_kernel<<<2048, 256, 0, stream>>>(x, xh, N * NDIM / 4);

    const int gblk = (N + 63) / 64;
    // layer 1: h_hi = bf16(relu([mean(x) | x] @ Wt1 + b1))   (no fp32 h)
    aggregate_bf16_kernel<<<(N + 15) / 16, 256, 0, stream>>>(xh, row_beg, degN, colA, aggh, aggl, N);
    gemm_mfma_kernel<<<gblk, 256, 0, stream>>>(aggh, aggl, xh, wt1h, wt1l, b1,
                                               (float*)0, hh, N, 1);
    // layer 2: out = [mean(h) | h] @ Wt2 + b2  (fp32, overwrites xh scratch in d_out)
    aggregate_bf16_kernel<<<(N + 15) / 16, 256, 0, stream>>>(hh, row_beg, degN, colA, aggh, aggl, N);
    gemm_mfma_kernel<<<gblk, 256, 0, stream>>>(aggh, aggl, hh, wt2h, wt2l, b2,
                                               out, (u16*)0, N, 0);
}